// Round 1
// baseline (984.263 us; speedup 1.0000x reference)
//
#include <hip/hip_runtime.h>
#include <math.h>

#define N 8192
#define D 128
#define NUM_CLASSES 64
#define MARGINF 0.4f
#define ALPHAF 1.2f
#define TF 10.0f
// pos threshold = ALPHA - MARGIN = 0.8

// ws layout (floats): [0..7] posAcc(+pad) | [8..8+N) rowW | [8+N..8+2N) rowN | [8+2N..8+3N) sq

__global__ void sq_kernel(const float* __restrict__ emb, float* __restrict__ sq) {
    int row = blockIdx.x * blockDim.x + threadIdx.x;
    if (row < N) {
        const float4* p = (const float4*)(emb + (size_t)row * D);
        float s = 0.f;
#pragma unroll
        for (int i = 0; i < D / 4; ++i) {
            float4 v = p[i];
            s += v.x * v.x + v.y * v.y + v.z * v.z + v.w * v.w;
        }
        sq[row] = s;
    }
}

__global__ __launch_bounds__(256) void pair_kernel(
    const float* __restrict__ emb, const int* __restrict__ labels,
    const float* __restrict__ sq, float* __restrict__ posAcc,
    float* __restrict__ rowW, float* __restrict__ rowN)
{
    // k-major tiles: As[k][i] = emb[r0+i][k], Bs[k][j] = emb[c0+j][k]
    __shared__ float As[D][64];
    __shared__ float Bs[D][64];

    const int r0 = blockIdx.y * 64;
    const int c0 = blockIdx.x * 64;
    const int t = threadIdx.x;

    // Stage both 64x128 tiles. 2048 float4 per tile, 8 per thread.
    // f = it*256 + t; row = f & 63 (lanes span rows -> LDS writes 2-way aliased = free)
#pragma unroll
    for (int it = 0; it < 8; ++it) {
        int f = it * 256 + t;
        int row = f & 63;
        int k4 = f >> 6;  // 0..31
        float4 va = *(const float4*)(emb + (size_t)(r0 + row) * D + k4 * 4);
        float4 vb = *(const float4*)(emb + (size_t)(c0 + row) * D + k4 * 4);
        As[k4 * 4 + 0][row] = va.x; As[k4 * 4 + 1][row] = va.y;
        As[k4 * 4 + 2][row] = va.z; As[k4 * 4 + 3][row] = va.w;
        Bs[k4 * 4 + 0][row] = vb.x; Bs[k4 * 4 + 1][row] = vb.y;
        Bs[k4 * 4 + 2][row] = vb.z; Bs[k4 * 4 + 3][row] = vb.w;
    }
    __syncthreads();

    const int tx = t & 15;   // col group
    const int ty = t >> 4;   // row group
    float acc[4][4] = {{0.f}};

#pragma unroll 8
    for (int k = 0; k < D; ++k) {
        float4 a = *(const float4*)(&As[k][ty * 4]);
        float4 b = *(const float4*)(&Bs[k][tx * 4]);
        acc[0][0] += a.x * b.x; acc[0][1] += a.x * b.y; acc[0][2] += a.x * b.z; acc[0][3] += a.x * b.w;
        acc[1][0] += a.y * b.x; acc[1][1] += a.y * b.y; acc[1][2] += a.y * b.z; acc[1][3] += a.y * b.w;
        acc[2][0] += a.z * b.x; acc[2][1] += a.z * b.y; acc[2][2] += a.z * b.z; acc[2][3] += a.z * b.w;
        acc[3][0] += a.w * b.x; acc[3][1] += a.w * b.y; acc[3][2] += a.w * b.z; acc[3][3] += a.w * b.w;
    }

    // Epilogue
    float sr[4], sc[4];
    int lr[4], lc[4];
#pragma unroll
    for (int d = 0; d < 4; ++d) {
        sr[d] = sq[r0 + ty * 4 + d];
        sc[d] = sq[c0 + tx * 4 + d];
        lr[d] = labels[r0 + ty * 4 + d];
        lc[d] = labels[c0 + tx * 4 + d];
    }

    float pos = 0.f;
    float wsum[4] = {0.f, 0.f, 0.f, 0.f};
    float nsum[4] = {0.f, 0.f, 0.f, 0.f};
#pragma unroll
    for (int i = 0; i < 4; ++i) {
#pragma unroll
        for (int j = 0; j < 4; ++j) {
            int r = r0 + ty * 4 + i;
            int c = c0 + tx * 4 + j;
            float dist = sr[i] + sc[j] - 2.f * acc[i][j];
            if (lr[i] == lc[j]) {
                if (r != c && dist > (ALPHAF - MARGINF)) pos += dist - (ALPHAF - MARGINF);
            } else if (dist < ALPHAF) {
                float gap = ALPHAF - dist;
                float w = __expf(TF * gap);
                wsum[i] += w;
                nsum[i] += gap * w;
            }
        }
    }

    // pos: reduce across full wave, one atomic per wave
    float p = pos;
#pragma unroll
    for (int m = 1; m < 64; m <<= 1) p += __shfl_xor(p, m, 64);
    if ((t & 63) == 0) atomicAdd(posAcc, p);

    // row sums: reduce across tx (16-lane groups), one atomic per row per block
#pragma unroll
    for (int i = 0; i < 4; ++i) {
        float w = wsum[i];
        float nn = nsum[i];
#pragma unroll
        for (int m = 1; m < 16; m <<= 1) {
            w += __shfl_xor(w, m, 16);
            nn += __shfl_xor(nn, m, 16);
        }
        if (tx == 0) {
            atomicAdd(&rowW[r0 + ty * 4 + i], w);
            atomicAdd(&rowN[r0 + ty * 4 + i], nn);
        }
    }
}

__global__ void finalize_kernel(const int* __restrict__ labels,
                                const float* __restrict__ rowW,
                                const float* __restrict__ rowN,
                                const float* __restrict__ posAcc,
                                float* __restrict__ out)
{
    __shared__ float cw[NUM_CLASSES];
    __shared__ float cn[NUM_CLASSES];
    int t = threadIdx.x;
    if (t < NUM_CLASSES) { cw[t] = 0.f; cn[t] = 0.f; }
    __syncthreads();
    for (int i = t; i < N; i += blockDim.x) {
        int c = labels[i];
        atomicAdd(&cw[c], rowW[i]);
        atomicAdd(&cn[c], rowN[i]);
    }
    __syncthreads();
    if (t < NUM_CLASSES) {
        float v = (cw[t] > 0.f) ? (cn[t] / cw[t]) : 0.f;
#pragma unroll
        for (int m = 1; m < 64; m <<= 1) v += __shfl_xor(v, m, 64);
        if (t == 0) {
            out[0] = posAcc[0] + v;
            out[1] = (float)N;
        }
    }
}

extern "C" void kernel_launch(void* const* d_in, const int* in_sizes, int n_in,
                              void* d_out, int out_size, void* d_ws, size_t ws_size,
                              hipStream_t stream) {
    const float* emb = (const float*)d_in[0];
    const int* labels = (const int*)d_in[1];
    float* out = (float*)d_out;
    float* ws = (float*)d_ws;

    float* posAcc = ws;            // 1 (+7 pad)
    float* rowW = ws + 8;          // N
    float* rowN = ws + 8 + N;      // N
    float* sq = ws + 8 + 2 * N;    // N (fully overwritten, no init needed)

    // zero pos accumulator + row accumulators
    hipMemsetAsync(d_ws, 0, (size_t)(8 + 2 * N) * sizeof(float), stream);

    sq_kernel<<<dim3(N / 256), dim3(256), 0, stream>>>(emb, sq);

    dim3 grid(N / 64, N / 64);
    pair_kernel<<<grid, dim3(256), 0, stream>>>(emb, labels, sq, posAcc, rowW, rowN);

    finalize_kernel<<<dim3(1), dim3(256), 0, stream>>>(labels, rowW, rowN, posAcc, out);
}

// Round 2
// 302.533 us; speedup vs baseline: 3.2534x; 3.2534x over previous
//
#include <hip/hip_runtime.h>
#include <math.h>

#define N 8192
#define D 128
#define NUM_CLASSES 64
#define POS_TH 0.8f   // ALPHA - MARGIN
#define ALPHAF 1.2f
#define TF 10.0f

typedef __attribute__((ext_vector_type(8))) short short8;   // 8 x bf16 (4 VGPRs)
typedef __attribute__((ext_vector_type(4))) float f32x4;

// ws layout (floats):
//  [0..8)        posAcc (+pad)
//  [8..8+N)      rowW
//  [8+N..8+2N)   rowN
//  [8+2N..8+4N)  lsq  (float2 per row: {sq, (float)label})
//  [8+4N.. )     ebf  (N*D bf16 = N*64 floats)

static __device__ __forceinline__ unsigned short f2bf(float x) {
    unsigned u = __float_as_uint(x);
    u = u + 0x7fffu + ((u >> 16) & 1u);   // RNE
    return (unsigned short)(u >> 16);
}

// 64 rows per block, 4 threads per row (32 elems each)
__global__ __launch_bounds__(256) void prep_kernel(
    const float* __restrict__ emb, const int* __restrict__ labels,
    float2* __restrict__ lsq, unsigned short* __restrict__ ebf)
{
    int t = threadIdx.x;
    int row = blockIdx.x * 64 + (t >> 2);
    int quad = t & 3;
    const float4* src = (const float4*)(emb + (size_t)row * D + quad * 32);
    ushort4* dst = (ushort4*)(ebf + (size_t)row * D + quad * 32);
    float s = 0.f;
#pragma unroll
    for (int i = 0; i < 8; ++i) {
        float4 v = src[i];
        s += v.x * v.x + v.y * v.y + v.z * v.z + v.w * v.w;
        ushort4 o;
        o.x = f2bf(v.x); o.y = f2bf(v.y); o.z = f2bf(v.z); o.w = f2bf(v.w);
        dst[i] = o;
    }
    s += __shfl_xor(s, 1, 4);
    s += __shfl_xor(s, 2, 4);
    if (quad == 0) lsq[row] = make_float2(s, (float)labels[row]);
}

__global__ __launch_bounds__(256) void pair_kernel(
    const unsigned short* __restrict__ ebf, const float2* __restrict__ lsq,
    float* __restrict__ posAcc, float* __restrict__ rowW, float* __restrict__ rowN)
{
    // 128x128 bf16 tiles, XOR-swizzled 16B granules: slot(r,g) = g ^ (r&7)
    __shared__ short As[128 * 128];
    __shared__ short Bs[128 * 128];

    const int t = threadIdx.x;
    const int r0 = blockIdx.y * 128;
    const int c0 = blockIdx.x * 128;

    // ---- stage tiles (each row = 16 granules of 8 bf16) ----
    const uint4* src = (const uint4*)ebf;  // 1 uint4 = 8 bf16
#pragma unroll
    for (int it = 0; it < 8; ++it) {
        int f = it * 256 + t;
        int r = f >> 4;        // 0..127
        int g = f & 15;        // 0..15
        uint4 va = src[(size_t)(r0 + r) * 16 + g];
        uint4 vb = src[(size_t)(c0 + r) * 16 + g];
        *(uint4*)(&As[r * 128 + ((g ^ (r & 7)) << 3)]) = va;
        *(uint4*)(&Bs[r * 128 + ((g ^ (r & 7)) << 3)]) = vb;
    }
    __syncthreads();

    // ---- MFMA: wave computes 64x64 sub-tile ----
    const int lane = t & 63;
    const int w = t >> 6;
    const int wy = w >> 1, wx = w & 1;
    const int m = lane & 15;   // fragment row/col within 16
    const int q = lane >> 4;   // quad group

    f32x4 acc[4][4];
#pragma unroll
    for (int i = 0; i < 4; ++i)
#pragma unroll
        for (int j = 0; j < 4; ++j) acc[i][j] = (f32x4){0.f, 0.f, 0.f, 0.f};

    const int sw = m & 7;  // swizzle key for fragment reads
#pragma unroll
    for (int kk = 0; kk < 4; ++kk) {
        short8 a[4], b[4];
        int g = kk * 4 + q;
        int gs = (g ^ sw) << 3;
#pragma unroll
        for (int rt = 0; rt < 4; ++rt) {
            int rl = wy * 64 + rt * 16 + m;
            a[rt] = *(const short8*)(&As[rl * 128 + gs]);
        }
#pragma unroll
        for (int ct = 0; ct < 4; ++ct) {
            int cl = wx * 64 + ct * 16 + m;
            b[ct] = *(const short8*)(&Bs[cl * 128 + gs]);
        }
#pragma unroll
        for (int rt = 0; rt < 4; ++rt)
#pragma unroll
            for (int ct = 0; ct < 4; ++ct)
                acc[rt][ct] = __builtin_amdgcn_mfma_f32_16x16x32_bf16(
                    a[rt], b[ct], acc[rt][ct], 0, 0, 0);
    }

    // ---- fused epilogue ----
    // C/D layout: col = lane&15, row = (lane>>4)*4 + reg
    float sc[4]; float lc[4];
#pragma unroll
    for (int ct = 0; ct < 4; ++ct) {
        float2 v = lsq[c0 + wx * 64 + ct * 16 + m];
        sc[ct] = v.x; lc[ct] = v.y;
    }

    float pos = 0.f;
    float wsum[4][4], nsum[4][4];
#pragma unroll
    for (int i = 0; i < 4; ++i)
#pragma unroll
        for (int j = 0; j < 4; ++j) { wsum[i][j] = 0.f; nsum[i][j] = 0.f; }
    bool anyneg = false;

#pragma unroll
    for (int rt = 0; rt < 4; ++rt) {
        float sr[4]; float lr[4];
#pragma unroll
        for (int reg = 0; reg < 4; ++reg) {
            float2 v = lsq[r0 + wy * 64 + rt * 16 + q * 4 + reg];
            sr[reg] = v.x; lr[reg] = v.y;
        }
#pragma unroll
        for (int ct = 0; ct < 4; ++ct) {
            f32x4 A = acc[rt][ct];
            int c = c0 + wx * 64 + ct * 16 + m;
#pragma unroll
            for (int reg = 0; reg < 4; ++reg) {
                int r = r0 + wy * 64 + rt * 16 + q * 4 + reg;
                float dist = sr[reg] + sc[ct] - 2.f * A[reg];
                if (lr[reg] == lc[ct]) {
                    if (r != c && dist > POS_TH) pos += dist - POS_TH;
                } else if (dist < ALPHAF) {
                    float gap = ALPHAF - dist;
                    float wv = __expf(TF * gap);
                    wsum[rt][reg] += wv;
                    nsum[rt][reg] += gap * wv;
                    anyneg = true;
                }
            }
        }
    }

    // pos: full-wave reduce, one atomic per wave
#pragma unroll
    for (int off = 1; off < 64; off <<= 1) pos += __shfl_xor(pos, off, 64);
    if (lane == 0) atomicAdd(posAcc, pos);

    // neg rows: nearly always all-zero -> skip entirely
    if (__any(anyneg)) {
#pragma unroll
        for (int rt = 0; rt < 4; ++rt)
#pragma unroll
            for (int reg = 0; reg < 4; ++reg) {
                float wv = wsum[rt][reg];
                float nn = nsum[rt][reg];
#pragma unroll
                for (int off = 1; off < 16; off <<= 1) {
                    wv += __shfl_xor(wv, off, 16);
                    nn += __shfl_xor(nn, off, 16);
                }
                if (m == 0) {
                    int r = r0 + wy * 64 + rt * 16 + q * 4 + reg;
                    atomicAdd(&rowW[r], wv);
                    atomicAdd(&rowN[r], nn);
                }
            }
    }
}

__global__ void finalize_kernel(const int* __restrict__ labels,
                                const float* __restrict__ rowW,
                                const float* __restrict__ rowN,
                                const float* __restrict__ posAcc,
                                float* __restrict__ out)
{
    __shared__ float cw[NUM_CLASSES];
    __shared__ float cn[NUM_CLASSES];
    int t = threadIdx.x;
    if (t < NUM_CLASSES) { cw[t] = 0.f; cn[t] = 0.f; }
    __syncthreads();
    for (int i = t; i < N; i += blockDim.x) {
        int c = labels[i];
        atomicAdd(&cw[c], rowW[i]);
        atomicAdd(&cn[c], rowN[i]);
    }
    __syncthreads();
    if (t < NUM_CLASSES) {
        float v = (cw[t] > 0.f) ? (cn[t] / cw[t]) : 0.f;
#pragma unroll
        for (int mm = 1; mm < 64; mm <<= 1) v += __shfl_xor(v, mm, 64);
        if (t == 0) {
            out[0] = posAcc[0] + v;
            out[1] = (float)N;
        }
    }
}

extern "C" void kernel_launch(void* const* d_in, const int* in_sizes, int n_in,
                              void* d_out, int out_size, void* d_ws, size_t ws_size,
                              hipStream_t stream) {
    const float* emb = (const float*)d_in[0];
    const int* labels = (const int*)d_in[1];
    float* out = (float*)d_out;
    float* ws = (float*)d_ws;

    float* posAcc = ws;                         // 8
    float* rowW = ws + 8;                       // N
    float* rowN = ws + 8 + N;                   // N
    float2* lsq = (float2*)(ws + 8 + 2 * N);    // 2N floats
    unsigned short* ebf = (unsigned short*)(ws + 8 + 4 * N);  // N*D bf16

    hipMemsetAsync(d_ws, 0, (size_t)(8 + 2 * N) * sizeof(float), stream);

    prep_kernel<<<dim3(N / 64), dim3(256), 0, stream>>>(emb, labels, lsq, ebf);

    dim3 grid(N / 128, N / 128);
    pair_kernel<<<grid, dim3(256), 0, stream>>>(ebf, lsq, posAcc, rowW, rowN);

    finalize_kernel<<<dim3(1), dim3(256), 0, stream>>>(labels, rowW, rowN, posAcc, out);
}

// Round 3
// 149.594 us; speedup vs baseline: 6.5795x; 2.0224x over previous
//
#include <hip/hip_runtime.h>
#include <math.h>

#define N 8192
#define D 128
#define NUM_CLASSES 64
#define POS_TH 0.8f   // ALPHA - MARGIN
#define ALPHAF 1.2f
#define TF 10.0f
#define NBLK 4096     // (N/128)^2 pair blocks

typedef __attribute__((ext_vector_type(8))) short short8;   // 8 x bf16 (4 VGPRs)
typedef __attribute__((ext_vector_type(4))) float f32x4;

// ws layout (floats):
//  [0..8)            pad
//  [8..8+N)          rowW
//  [8+N..8+2N)       rowN
//  [8+2N..8+4N)      lsq  (float2 per row: {sq, (float)label})
//  [8+4N..8+4N+NBLK) posPart (one partial per pair block; fully written, no init)
//  [8+4N+NBLK.. )    ebf  (N*D bf16 = N*64 floats), 16B-aligned

static __device__ __forceinline__ unsigned short f2bf(float x) {
    unsigned u = __float_as_uint(x);
    u = u + 0x7fffu + ((u >> 16) & 1u);   // RNE
    return (unsigned short)(u >> 16);
}

// 64 rows per block, 4 threads per row (32 elems each)
__global__ __launch_bounds__(256) void prep_kernel(
    const float* __restrict__ emb, const int* __restrict__ labels,
    float2* __restrict__ lsq, unsigned short* __restrict__ ebf)
{
    int t = threadIdx.x;
    int row = blockIdx.x * 64 + (t >> 2);
    int quad = t & 3;
    const float4* src = (const float4*)(emb + (size_t)row * D + quad * 32);
    ushort4* dst = (ushort4*)(ebf + (size_t)row * D + quad * 32);
    float s = 0.f;
#pragma unroll
    for (int i = 0; i < 8; ++i) {
        float4 v = src[i];
        s += v.x * v.x + v.y * v.y + v.z * v.z + v.w * v.w;
        ushort4 o;
        o.x = f2bf(v.x); o.y = f2bf(v.y); o.z = f2bf(v.z); o.w = f2bf(v.w);
        dst[i] = o;
    }
    s += __shfl_xor(s, 1, 4);
    s += __shfl_xor(s, 2, 4);
    if (quad == 0) lsq[row] = make_float2(s, (float)labels[row]);
}

__global__ __launch_bounds__(256) void pair_kernel(
    const unsigned short* __restrict__ ebf, const float2* __restrict__ lsq,
    float* __restrict__ posPart, float* __restrict__ rowW, float* __restrict__ rowN)
{
    // 128x128 bf16 tiles, XOR-swizzled 16B granules: slot(r,g) = g ^ (r&7)
    __shared__ short As[128 * 128];
    __shared__ short Bs[128 * 128];
    __shared__ float wpos[4];

    const int t = threadIdx.x;
    const int r0 = blockIdx.y * 128;
    const int c0 = blockIdx.x * 128;

    // ---- stage tiles (each row = 16 granules of 8 bf16) ----
    const uint4* src = (const uint4*)ebf;  // 1 uint4 = 8 bf16
#pragma unroll
    for (int it = 0; it < 8; ++it) {
        int f = it * 256 + t;
        int r = f >> 4;        // 0..127
        int g = f & 15;        // 0..15
        uint4 va = src[(size_t)(r0 + r) * 16 + g];
        uint4 vb = src[(size_t)(c0 + r) * 16 + g];
        *(uint4*)(&As[r * 128 + ((g ^ (r & 7)) << 3)]) = va;
        *(uint4*)(&Bs[r * 128 + ((g ^ (r & 7)) << 3)]) = vb;
    }
    __syncthreads();

    // ---- MFMA: wave computes 64x64 sub-tile ----
    const int lane = t & 63;
    const int w = t >> 6;
    const int wy = w >> 1, wx = w & 1;
    const int m = lane & 15;   // fragment row/col within 16
    const int q = lane >> 4;   // quad group

    f32x4 acc[4][4];
#pragma unroll
    for (int i = 0; i < 4; ++i)
#pragma unroll
        for (int j = 0; j < 4; ++j) acc[i][j] = (f32x4){0.f, 0.f, 0.f, 0.f};

    const int sw = m & 7;  // swizzle key for fragment reads
#pragma unroll
    for (int kk = 0; kk < 4; ++kk) {
        short8 a[4], b[4];
        int g = kk * 4 + q;
        int gs = (g ^ sw) << 3;
#pragma unroll
        for (int rt = 0; rt < 4; ++rt) {
            int rl = wy * 64 + rt * 16 + m;
            a[rt] = *(const short8*)(&As[rl * 128 + gs]);
        }
#pragma unroll
        for (int ct = 0; ct < 4; ++ct) {
            int cl = wx * 64 + ct * 16 + m;
            b[ct] = *(const short8*)(&Bs[cl * 128 + gs]);
        }
#pragma unroll
        for (int rt = 0; rt < 4; ++rt)
#pragma unroll
            for (int ct = 0; ct < 4; ++ct)
                acc[rt][ct] = __builtin_amdgcn_mfma_f32_16x16x32_bf16(
                    a[rt], b[ct], acc[rt][ct], 0, 0, 0);
    }

    // ---- fused epilogue ----
    // C/D layout: col = lane&15, row = (lane>>4)*4 + reg
    float sc[4]; float lc[4];
#pragma unroll
    for (int ct = 0; ct < 4; ++ct) {
        float2 v = lsq[c0 + wx * 64 + ct * 16 + m];
        sc[ct] = v.x; lc[ct] = v.y;
    }

    float pos = 0.f;
    float wsum[4][4], nsum[4][4];
#pragma unroll
    for (int i = 0; i < 4; ++i)
#pragma unroll
        for (int j = 0; j < 4; ++j) { wsum[i][j] = 0.f; nsum[i][j] = 0.f; }
    bool anyneg = false;

#pragma unroll
    for (int rt = 0; rt < 4; ++rt) {
        float sr[4]; float lr[4];
#pragma unroll
        for (int reg = 0; reg < 4; ++reg) {
            float2 v = lsq[r0 + wy * 64 + rt * 16 + q * 4 + reg];
            sr[reg] = v.x; lr[reg] = v.y;
        }
#pragma unroll
        for (int ct = 0; ct < 4; ++ct) {
            f32x4 A = acc[rt][ct];
            int c = c0 + wx * 64 + ct * 16 + m;
#pragma unroll
            for (int reg = 0; reg < 4; ++reg) {
                int r = r0 + wy * 64 + rt * 16 + q * 4 + reg;
                float dist = sr[reg] + sc[ct] - 2.f * A[reg];
                if (lr[reg] == lc[ct]) {
                    if (r != c && dist > POS_TH) pos += dist - POS_TH;
                } else if (dist < ALPHAF) {
                    float gap = ALPHAF - dist;
                    float wv = __expf(TF * gap);
                    wsum[rt][reg] += wv;
                    nsum[rt][reg] += gap * wv;
                    anyneg = true;
                }
            }
        }
    }

    // pos: full-wave reduce -> per-block partial (NO global atomic)
#pragma unroll
    for (int off = 1; off < 64; off <<= 1) pos += __shfl_xor(pos, off, 64);
    if (lane == 0) wpos[w] = pos;

    // neg rows: nearly always all-zero -> skip entirely (cold path keeps atomics)
    if (__any(anyneg)) {
#pragma unroll
        for (int rt = 0; rt < 4; ++rt)
#pragma unroll
            for (int reg = 0; reg < 4; ++reg) {
                float wv = wsum[rt][reg];
                float nn = nsum[rt][reg];
#pragma unroll
                for (int off = 1; off < 16; off <<= 1) {
                    wv += __shfl_xor(wv, off, 16);
                    nn += __shfl_xor(nn, off, 16);
                }
                if (m == 0) {
                    int r = r0 + wy * 64 + rt * 16 + q * 4 + reg;
                    atomicAdd(&rowW[r], wv);
                    atomicAdd(&rowN[r], nn);
                }
            }
    }

    __syncthreads();
    if (t == 0)
        posPart[blockIdx.y * gridDim.x + blockIdx.x] = wpos[0] + wpos[1] + wpos[2] + wpos[3];
}

__global__ __launch_bounds__(256) void finalize_kernel(
    const int* __restrict__ labels,
    const float* __restrict__ rowW,
    const float* __restrict__ rowN,
    const float* __restrict__ posPart,
    float* __restrict__ out)
{
    __shared__ float cw[NUM_CLASSES];
    __shared__ float cn[NUM_CLASSES];
    __shared__ float pp[4];
    int t = threadIdx.x;
    if (t < NUM_CLASSES) { cw[t] = 0.f; cn[t] = 0.f; }
    __syncthreads();

    // sum pos partials: 4096 values, 16 per thread
    float ps = 0.f;
#pragma unroll
    for (int i = 0; i < NBLK / 256; ++i) ps += posPart[i * 256 + t];
#pragma unroll
    for (int off = 1; off < 64; off <<= 1) ps += __shfl_xor(ps, off, 64);
    if ((t & 63) == 0) pp[t >> 6] = ps;

    // per-class sums of row accumulators
    for (int i = t; i < N; i += blockDim.x) {
        int c = labels[i];
        atomicAdd(&cw[c], rowW[i]);
        atomicAdd(&cn[c], rowN[i]);
    }
    __syncthreads();
    if (t < NUM_CLASSES) {
        float v = (cw[t] > 0.f) ? (cn[t] / cw[t]) : 0.f;
#pragma unroll
        for (int mm = 1; mm < 64; mm <<= 1) v += __shfl_xor(v, mm, 64);
        if (t == 0) {
            out[0] = (pp[0] + pp[1] + pp[2] + pp[3]) + v;
            out[1] = (float)N;
        }
    }
}

extern "C" void kernel_launch(void* const* d_in, const int* in_sizes, int n_in,
                              void* d_out, int out_size, void* d_ws, size_t ws_size,
                              hipStream_t stream) {
    const float* emb = (const float*)d_in[0];
    const int* labels = (const int*)d_in[1];
    float* out = (float*)d_out;
    float* ws = (float*)d_ws;

    float* rowW = ws + 8;                       // N
    float* rowN = ws + 8 + N;                   // N
    float2* lsq = (float2*)(ws + 8 + 2 * N);    // 2N floats
    float* posPart = ws + 8 + 4 * N;            // NBLK floats (fully written)
    unsigned short* ebf = (unsigned short*)(ws + 8 + 4 * N + NBLK);  // N*D bf16

    // zero rowW/rowN (+pad)
    hipMemsetAsync(d_ws, 0, (size_t)(8 + 2 * N) * sizeof(float), stream);

    prep_kernel<<<dim3(N / 64), dim3(256), 0, stream>>>(emb, labels, lsq, ebf);

    dim3 grid(N / 128, N / 128);
    pair_kernel<<<grid, dim3(256), 0, stream>>>(ebf, lsq, posPart, rowW, rowN);

    finalize_kernel<<<dim3(1), dim3(256), 0, stream>>>(labels, rowW, rowN, posPart, out);
}

// Round 4
// 111.059 us; speedup vs baseline: 8.8625x; 1.3470x over previous
//
#include <hip/hip_runtime.h>
#include <math.h>

#define N 8192
#define D 128
#define NUM_CLASSES 64
#define POS_TH 0.8f   // ALPHA - MARGIN
#define ALPHAF 1.2f
#define TF 10.0f
#define NB 64         // N / 128
#define NBLK (NB * NB)

typedef __attribute__((ext_vector_type(8))) short short8;   // 8 x bf16
typedef __attribute__((ext_vector_type(4))) float f32x4;

// ws layout (floats):
//  [0..8)            pad
//  [8..8+N)          rowW   (zeroed by prep)
//  [8+N..8+2N)       rowN   (zeroed by prep)
//  [8+2N..8+4N)      lsq    (float2 per row: {sq, (float)label})
//  [8+4N..8+4N+NBLK) posPart (upper-tri entries written by pair; rest masked)
//  [8+4N+NBLK.. )    ebf    (N*D bf16)

static __device__ __forceinline__ unsigned short f2bf(float x) {
    unsigned u = __float_as_uint(x);
    u = u + 0x7fffu + ((u >> 16) & 1u);   // RNE
    return (unsigned short)(u >> 16);
}

// 64 rows per block; also zeroes this block's slice of rowW/rowN (replaces memset node)
__global__ __launch_bounds__(256) void prep_kernel(
    const float* __restrict__ emb, const int* __restrict__ labels,
    float2* __restrict__ lsq, unsigned short* __restrict__ ebf,
    float* __restrict__ rowW, float* __restrict__ rowN)
{
    int t = threadIdx.x;
    if (t < 64) {
        rowW[blockIdx.x * 64 + t] = 0.f;
        rowN[blockIdx.x * 64 + t] = 0.f;
    }
    int row = blockIdx.x * 64 + (t >> 2);
    int quad = t & 3;
    const float4* src = (const float4*)(emb + (size_t)row * D + quad * 32);
    ushort4* dst = (ushort4*)(ebf + (size_t)row * D + quad * 32);
    float s = 0.f;
#pragma unroll
    for (int i = 0; i < 8; ++i) {
        float4 v = src[i];
        s += v.x * v.x + v.y * v.y + v.z * v.z + v.w * v.w;
        ushort4 o;
        o.x = f2bf(v.x); o.y = f2bf(v.y); o.z = f2bf(v.z); o.w = f2bf(v.w);
        dst[i] = o;
    }
    s += __shfl_xor(s, 1, 4);
    s += __shfl_xor(s, 2, 4);
    if (quad == 0) lsq[row] = make_float2(s, (float)labels[row]);
}

// Upper-triangle 128x128 blocks; 512 threads = 8 waves, each wave 64x32 sub-tile.
__global__ __launch_bounds__(512) void pair_kernel(
    const unsigned short* __restrict__ ebf, const float2* __restrict__ lsq,
    float* __restrict__ posPart, float* __restrict__ rowW, float* __restrict__ rowN)
{
    __shared__ short As[128 * 128];
    __shared__ short Bs[128 * 128];
    __shared__ float2 lsqR[128];
    __shared__ float2 lsqC[128];
    __shared__ float wpos[8];

    const int bx = blockIdx.x, by = blockIdx.y;
    if (bx < by) return;   // lower triangle: nothing (uniform exit, before barriers)

    const int t = threadIdx.x;
    const int r0 = by * 128;
    const int c0 = bx * 128;

    // ---- stage tiles: XOR-swizzled 16B granules, slot(r,g) = g ^ (r&7) ----
    const uint4* src = (const uint4*)ebf;
#pragma unroll
    for (int it = 0; it < 4; ++it) {
        int f = it * 512 + t;
        int r = f >> 4;        // 0..127
        int g = f & 15;        // 0..15
        uint4 va = src[(size_t)(r0 + r) * 16 + g];
        uint4 vb = src[(size_t)(c0 + r) * 16 + g];
        int slot = (g ^ (r & 7)) << 3;
        *(uint4*)(&As[r * 128 + slot]) = va;
        *(uint4*)(&Bs[r * 128 + slot]) = vb;
    }
    if (t < 128) lsqR[t] = lsq[r0 + t];
    else if (t < 256) lsqC[t - 128] = lsq[c0 + (t - 128)];
    __syncthreads();

    // ---- MFMA ----
    const int lane = t & 63;
    const int w = t >> 6;
    const int wy = w >> 2;     // 0..1 (row 64-half)
    const int wx = w & 3;      // 0..3 (col 32-quarter)
    const int m = lane & 15;
    const int q = lane >> 4;
    const int sw = m & 7;

    f32x4 acc[4][2];
#pragma unroll
    for (int i = 0; i < 4; ++i)
#pragma unroll
        for (int j = 0; j < 2; ++j) acc[i][j] = (f32x4){0.f, 0.f, 0.f, 0.f};

#pragma unroll
    for (int kk = 0; kk < 4; ++kk) {
        int g = kk * 4 + q;
        int gs = (g ^ sw) << 3;
        short8 a[4], b[2];
#pragma unroll
        for (int rt = 0; rt < 4; ++rt)
            a[rt] = *(const short8*)(&As[(wy * 64 + rt * 16 + m) * 128 + gs]);
#pragma unroll
        for (int ct = 0; ct < 2; ++ct)
            b[ct] = *(const short8*)(&Bs[(wx * 32 + ct * 16 + m) * 128 + gs]);
#pragma unroll
        for (int rt = 0; rt < 4; ++rt)
#pragma unroll
            for (int ct = 0; ct < 2; ++ct)
                acc[rt][ct] = __builtin_amdgcn_mfma_f32_16x16x32_bf16(
                    a[rt], b[ct], acc[rt][ct], 0, 0, 0);
    }

    // ---- branch-free hot epilogue ----
    // u = dist - 0.8. pos term = same ? relu(u) : 0 (diagonal: dist_ii ~ +-0.15 -> relu 0).
    // md = min(u): trigger covers any dist < 1.2 (neg candidates); cold path rescans exactly.
    float scm[2], lc[2];
#pragma unroll
    for (int ct = 0; ct < 2; ++ct) {
        float2 v = lsqC[wx * 32 + ct * 16 + m];
        scm[ct] = v.x - POS_TH;
        lc[ct] = v.y;
    }

    float pos = 0.f;
    float md = 1e30f;
#pragma unroll
    for (int rt = 0; rt < 4; ++rt) {
        float sr[4], lr[4];
#pragma unroll
        for (int reg = 0; reg < 4; ++reg) {
            float2 v = lsqR[wy * 64 + rt * 16 + q * 4 + reg];
            sr[reg] = v.x; lr[reg] = v.y;
        }
#pragma unroll
        for (int ct = 0; ct < 2; ++ct) {
            f32x4 A = acc[rt][ct];
#pragma unroll
            for (int reg = 0; reg < 4; ++reg) {
                float u = fmaf(A[reg], -2.f, sr[reg]) + scm[ct];
                md = fminf(md, u);
                float rel = fmaxf(u, 0.f);
                pos += (lr[reg] == lc[ct]) ? rel : 0.f;
            }
        }
    }

    // ---- cold path: exact neg handling (never triggers off-diag on this data;
    //      diag blocks trigger via u_ii ~ -0.8 but find no lr!=lc negs) ----
    if (__any(md < (ALPHAF - POS_TH))) {
        const bool offd = (bx != by);
#pragma unroll
        for (int rt = 0; rt < 4; ++rt) {
            float sr[4], lr[4];
#pragma unroll
            for (int reg = 0; reg < 4; ++reg) {
                float2 v = lsqR[wy * 64 + rt * 16 + q * 4 + reg];
                sr[reg] = v.x; lr[reg] = v.y;
            }
#pragma unroll
            for (int ct = 0; ct < 2; ++ct) {
                f32x4 A = acc[rt][ct];
#pragma unroll
                for (int reg = 0; reg < 4; ++reg) {
                    float u = fmaf(A[reg], -2.f, sr[reg]) + scm[ct];
                    if (lr[reg] != lc[ct] && u < (ALPHAF - POS_TH)) {
                        float gap = (ALPHAF - POS_TH) - u;   // = ALPHA - dist
                        float wv = __expf(TF * gap);
                        int r = r0 + wy * 64 + rt * 16 + q * 4 + reg;
                        int c = c0 + wx * 32 + ct * 16 + m;
                        atomicAdd(&rowW[r], wv);
                        atomicAdd(&rowN[r], gap * wv);
                        if (offd) {
                            atomicAdd(&rowW[c], wv);
                            atomicAdd(&rowN[c], gap * wv);
                        }
                    }
                }
            }
        }
    }

    // ---- pos partial: off-diag counts twice (symmetry) ----
    if (bx != by) pos *= 2.f;
#pragma unroll
    for (int off = 1; off < 64; off <<= 1) pos += __shfl_xor(pos, off, 64);
    if (lane == 0) wpos[w] = pos;
    __syncthreads();
    if (t == 0) {
        float s = 0.f;
#pragma unroll
        for (int i = 0; i < 8; ++i) s += wpos[i];
        posPart[by * NB + bx] = s;
    }
}

__global__ __launch_bounds__(256) void finalize_kernel(
    const int* __restrict__ labels,
    const float* __restrict__ rowW,
    const float* __restrict__ rowN,
    const float* __restrict__ posPart,
    float* __restrict__ out)
{
    __shared__ float cw[NUM_CLASSES];
    __shared__ float cn[NUM_CLASSES];
    __shared__ float pp[4];
    int t = threadIdx.x;
    if (t < NUM_CLASSES) { cw[t] = 0.f; cn[t] = 0.f; }
    __syncthreads();

    // sum upper-triangle pos partials (lower-tri entries are untouched poison -> masked)
    float ps = 0.f;
    for (int i = t; i < NBLK; i += 256) {
        int bby = i >> 6, bbx = i & 63;
        if (bbx >= bby) ps += posPart[i];
    }
#pragma unroll
    for (int off = 1; off < 64; off <<= 1) ps += __shfl_xor(ps, off, 64);
    if ((t & 63) == 0) pp[t >> 6] = ps;

    for (int i = t; i < N; i += blockDim.x) {
        int c = labels[i];
        atomicAdd(&cw[c], rowW[i]);
        atomicAdd(&cn[c], rowN[i]);
    }
    __syncthreads();
    if (t < NUM_CLASSES) {
        float v = (cw[t] > 0.f) ? (cn[t] / cw[t]) : 0.f;
#pragma unroll
        for (int mm = 1; mm < 64; mm <<= 1) v += __shfl_xor(v, mm, 64);
        if (t == 0) {
            out[0] = (pp[0] + pp[1] + pp[2] + pp[3]) + v;
            out[1] = (float)N;
        }
    }
}

extern "C" void kernel_launch(void* const* d_in, const int* in_sizes, int n_in,
                              void* d_out, int out_size, void* d_ws, size_t ws_size,
                              hipStream_t stream) {
    const float* emb = (const float*)d_in[0];
    const int* labels = (const int*)d_in[1];
    float* out = (float*)d_out;
    float* ws = (float*)d_ws;

    float* rowW = ws + 8;
    float* rowN = ws + 8 + N;
    float2* lsq = (float2*)(ws + 8 + 2 * N);
    float* posPart = ws + 8 + 4 * N;
    unsigned short* ebf = (unsigned short*)(ws + 8 + 4 * N + NBLK);

    prep_kernel<<<dim3(N / 64), dim3(256), 0, stream>>>(emb, labels, lsq, ebf, rowW, rowN);

    dim3 grid(NB, NB);
    pair_kernel<<<grid, dim3(512), 0, stream>>>(ebf, lsq, posPart, rowW, rowN);

    finalize_kernel<<<dim3(1), dim3(256), 0, stream>>>(labels, rowW, rowN, posPart, out);
}